// Round 1
// baseline (847.267 us; speedup 1.0000x reference)
//
#include <hip/hip_runtime.h>

// NgramAttentions: flash-style fused attention per channel.
//   C=8, L=4096, N=4096, D=128, V=100000
//   out[l, c*128+d] = sum_n a[c,l,n] * emb[c,n,d],  a = exp(u)*clip(mask) / (rowsum + 1e-10)
//   u = (H . E^T)/sqrt(128).  softmax(W_channel) over size-1 axis == 1.0 -> ignored.

typedef __bf16 bf16_t;
typedef bf16_t bf16x8 __attribute__((ext_vector_type(8)));
typedef bf16_t bf16x4 __attribute__((ext_vector_type(4)));
typedef bf16_t bf16x2 __attribute__((ext_vector_type(2)));
typedef float  f32x16 __attribute__((ext_vector_type(16)));
typedef float  f32x4  __attribute__((ext_vector_type(4)));

#define C_ 8
#define L_ 4096
#define N_ 4096
#define D_ 128

__global__ __launch_bounds__(512) void ngram_attn_kernel(
    const int* __restrict__ seq,      // [C, N] int32
    const float* __restrict__ hidden, // [L, D]
    const float* __restrict__ mask,   // [C, L, N]
    const float* __restrict__ Wemb,   // [V, D]
    float* __restrict__ out)          // [L, C*D]
{
  // LDS: all row strides 136 bf16 = 272 B (16B-aligned, +8 pad breaks 128B stride)
  __shared__ bf16_t Hs [128][136];  // H tile  [l][d]
  __shared__ bf16_t End[128][136];  // E tile  [n][d]  (GEMM1 A operand)
  __shared__ bf16_t Et [128][136];  // E tile  [d][n]  (GEMM2 B operand)
  __shared__ bf16_t Ps [128][136];  // P tile  [l][n]  (GEMM2 A operand)
  __shared__ float  dpart[4][128];
  __shared__ float  dinv[128];

  const int bid  = blockIdx.x;
  const int c    = bid & 7;          // channel -> same XCD for L2 gather locality
  const int l0   = (bid >> 3) * 128;
  const int tid  = threadIdx.x;
  const int wv   = tid >> 6;
  const int lane = tid & 63;
  const int mrow = lane & 31;        // MFMA m / col index
  const int hi   = lane >> 5;        // lane half
  const int nb   = wv & 3;           // GEMM1: n-slab   | GEMM2: l-slab
  const int lh   = wv >> 2;          // GEMM1: l-half   | GEMM2: d-half

  const float inv_temper = 0.08838834764831845f;  // 1/sqrt(128)

  // ---- stage H tile once: [128 l][128 d] fp32 -> bf16 LDS
  #pragma unroll
  for (int rep = 0; rep < 8; ++rep) {
    int u = tid + rep * 512;          // 0..4095 float4 units
    int q = u & 31, r = u >> 5;       // col-group, row
    f32x4 h4 = *(const f32x4*)(hidden + (size_t)(l0 + r) * D_ + q * 4);
    bf16x4 hb = { (bf16_t)h4[0], (bf16_t)h4[1], (bf16_t)h4[2], (bf16_t)h4[3] };
    *(bf16x4*)&Hs[r][q * 4] = hb;
  }

  f32x16 Oacc0, Oacc1;
  #pragma unroll
  for (int i = 0; i < 16; ++i) { Oacc0[i] = 0.f; Oacc1[i] = 0.f; }
  float dsum0 = 0.f, dsum1 = 0.f;

  const int* seq_c = seq + (size_t)c * N_;

  #pragma unroll 1
  for (int nt = 0; nt < 32; ++nt) {
    const int n0 = nt * 128;
    __syncthreads();  // prev GEMM2 done reading E/P (and H ready on first iter)

    // ---- stage E tile, dual layout (gather + fp32->bf16)
    #pragma unroll
    for (int rep = 0; rep < 2; ++rep) {
      int u  = tid + rep * 512;       // 0..1023 units: 64 n-pairs x 16 d-groups
      int np = u & 63, g = u >> 6;
      int n1 = 2 * np, n2 = n1 + 1;
      int i1 = seq_c[n0 + n1], i2 = seq_c[n0 + n2];
      const f32x4* r1 = (const f32x4*)(Wemb + (size_t)i1 * D_ + g * 8);
      const f32x4* r2 = (const f32x4*)(Wemb + (size_t)i2 * D_ + g * 8);
      f32x4 a0 = r1[0], a1 = r1[1];
      f32x4 b0 = r2[0], b1 = r2[1];
      bf16x8 e1 = { (bf16_t)a0[0], (bf16_t)a0[1], (bf16_t)a0[2], (bf16_t)a0[3],
                    (bf16_t)a1[0], (bf16_t)a1[1], (bf16_t)a1[2], (bf16_t)a1[3] };
      bf16x8 e2 = { (bf16_t)b0[0], (bf16_t)b0[1], (bf16_t)b0[2], (bf16_t)b0[3],
                    (bf16_t)b1[0], (bf16_t)b1[1], (bf16_t)b1[2], (bf16_t)b1[3] };
      *(bf16x8*)&End[n1][g * 8] = e1;
      *(bf16x8*)&End[n2][g * 8] = e2;
      #pragma unroll
      for (int i = 0; i < 8; ++i) {   // transposed copy, packed dword writes
        bf16x2 t = { e1[i], e2[i] };
        *(bf16x2*)&Et[g * 8 + i][n1] = t;
      }
    }
    __syncthreads();

    // ---- prefetch mask in S^T C-layout (col=l, rows=n) to hide HBM latency
    f32x4 mreg[2][4];
    #pragma unroll
    for (int cb = 0; cb < 2; ++cb) {
      int lg = l0 + lh * 64 + cb * 32 + mrow;
      const float* mp = mask + ((size_t)c * L_ + lg) * N_ + n0 + nb * 32 + 4 * hi;
      #pragma unroll
      for (int g = 0; g < 4; ++g)
        mreg[cb][g] = *(const f32x4*)(mp + 8 * g);
    }

    // ---- GEMM1: S^T[n][l] = E . H^T   (M=n slab of 32, N=l 2x32, K=d 128)
    f32x16 S0, S1;
    #pragma unroll
    for (int i = 0; i < 16; ++i) { S0[i] = 0.f; S1[i] = 0.f; }
    #pragma unroll
    for (int ks = 0; ks < 8; ++ks) {
      bf16x8 a = *(const bf16x8*)&End[nb * 32 + mrow][ks * 16 + hi * 8];
      bf16x8 b0 = *(const bf16x8*)&Hs[lh * 64 + 0  + mrow][ks * 16 + hi * 8];
      bf16x8 b1 = *(const bf16x8*)&Hs[lh * 64 + 32 + mrow][ks * 16 + hi * 8];
      S0 = __builtin_amdgcn_mfma_f32_32x32x16_bf16(a, b0, S0, 0, 0, 0);
      S1 = __builtin_amdgcn_mfma_f32_32x32x16_bf16(a, b1, S1, 0, 0, 0);
    }

    // ---- exp * mask, denom accumulate, write P (bf16)
    #pragma unroll
    for (int cb = 0; cb < 2; ++cb) {
      int lrow = lh * 64 + cb * 32 + mrow;
      #pragma unroll
      for (int g = 0; g < 4; ++g) {
        bf16x4 pw;
        float lsum = 0.f;
        #pragma unroll
        for (int j = 0; j < 4; ++j) {
          float s = (cb == 0) ? S0[4 * g + j] : S1[4 * g + j];
          float m = mreg[cb][g][j];
          m = fminf(fmaxf(m, 0.f), 1.f);
          float wval = __expf(s * inv_temper) * m;
          lsum += wval;
          pw[j] = (bf16_t)wval;
        }
        if (cb == 0) dsum0 += lsum; else dsum1 += lsum;
        *(bf16x4*)&Ps[lrow][nb * 32 + 8 * g + 4 * hi] = pw;
      }
    }
    __syncthreads();

    // ---- GEMM2: O[l][d] += P . E   (M=l slab of 32, N=d 2x32, K=n 128)
    #pragma unroll
    for (int ks = 0; ks < 8; ++ks) {
      bf16x8 a = *(const bf16x8*)&Ps[nb * 32 + mrow][ks * 16 + hi * 8];   // ls = nb
      bf16x8 b0 = *(const bf16x8*)&Et[lh * 64 + 0  + mrow][ks * 16 + hi * 8]; // dh = lh
      bf16x8 b1 = *(const bf16x8*)&Et[lh * 64 + 32 + mrow][ks * 16 + hi * 8];
      Oacc0 = __builtin_amdgcn_mfma_f32_32x32x16_bf16(a, b0, Oacc0, 0, 0, 0);
      Oacc1 = __builtin_amdgcn_mfma_f32_32x32x16_bf16(a, b1, Oacc1, 0, 0, 0);
    }
  }

  // ---- finalize denominators (per-l sums across the 4 n-slabs)
  {
    float v0 = dsum0 + __shfl_xor(dsum0, 32, 64);
    float v1 = dsum1 + __shfl_xor(dsum1, 32, 64);
    if (hi == 0) {
      dpart[nb][lh * 64 + 0  + mrow] = v0;
      dpart[nb][lh * 64 + 32 + mrow] = v1;
    }
  }
  __syncthreads();
  if (tid < 128) {
    float s = dpart[0][tid] + dpart[1][tid] + dpart[2][tid] + dpart[3][tid] + 1e-10f;
    dinv[tid] = 1.0f / s;
  }
  __syncthreads();

  // ---- epilogue: normalize + store
  #pragma unroll
  for (int r = 0; r < 16; ++r) {
    int row  = (r & 3) + 8 * (r >> 2) + 4 * hi;   // C/D layout row
    int lloc = nb * 32 + row;                     // ls = nb
    float inv = dinv[lloc];
    size_t base = (size_t)(l0 + lloc) * (C_ * D_) + c * D_ + lh * 64 + mrow;
    out[base]      = Oacc0[r] * inv;
    out[base + 32] = Oacc1[r] * inv;
  }
}

extern "C" void kernel_launch(void* const* d_in, const int* in_sizes, int n_in,
                              void* d_out, int out_size, void* d_ws, size_t ws_size,
                              hipStream_t stream) {
  (void)in_sizes; (void)n_in; (void)out_size; (void)d_ws; (void)ws_size;
  const int*   seq    = (const int*)d_in[0];
  const float* hidden = (const float*)d_in[1];
  const float* mask   = (const float*)d_in[2];
  // d_in[3] = channel_ids (unused), d_in[5] = W_channel (softmax over size-1 dim == 1)
  const float* Wemb   = (const float*)d_in[4];
  float* out = (float*)d_out;
  ngram_attn_kernel<<<dim3(256), dim3(512), 0, stream>>>(seq, hidden, mask, Wemb, out);
}

// Round 2
// 830.672 us; speedup vs baseline: 1.0200x; 1.0200x over previous
//
#include <hip/hip_runtime.h>

// NgramAttentions, round 2: S-orientation (mask coalesced), H in registers,
// register-prefetch software pipeline, nontemporal mask/out streams.
//   C=8, L=4096, N=4096, D=128. softmax(W_channel) over size-1 axis == 1 -> ignored.

typedef __bf16 bf16_t;
typedef bf16_t bf16x8 __attribute__((ext_vector_type(8)));
typedef bf16_t bf16x2 __attribute__((ext_vector_type(2)));
typedef float  f32x16 __attribute__((ext_vector_type(16)));
typedef float  f32x4  __attribute__((ext_vector_type(4)));

#define C_ 8
#define L_ 4096
#define N_ 4096
#define D_ 128

__global__ __launch_bounds__(512, 2) void ngram_attn_kernel(
    const int* __restrict__ seq,      // [C, N] int32
    const float* __restrict__ hidden, // [L, D]
    const float* __restrict__ mask,   // [C, L, N]
    const float* __restrict__ Wemb,   // [V, D]
    float* __restrict__ out)          // [L, C*D]
{
  // LDS (row stride 136 bf16 = 272 B = 68 dw === 4 mod 32 -> b128 reads conflict-free)
  __shared__ bf16_t End[128][136];  // E tile [n][d]  (GEMM1 B)
  __shared__ bf16_t Et [128][136];  // E tile [d][n]  (GEMM2 B)
  __shared__ bf16_t Ps [128][136];  // P tile [l][n]  (GEMM2 A)
  __shared__ float  dpart[2][128];
  __shared__ float  dinv[128];

  const int bid  = blockIdx.x;
  const int c    = bid & 7;          // channel -> XCD-stable for gather L2 reuse
  const int l0   = (bid >> 3) * 128;
  const int tid  = threadIdx.x;
  const int wv   = tid >> 6;
  const int lane = tid & 63;
  const int mrow = lane & 31;
  const int hi   = lane >> 5;
  const int lsl  = wv & 3;           // l slab (32 rows) for GEMM1-A / GEMM2-A
  const int nh   = wv >> 2;          // GEMM1: n half (64) | GEMM2: d half (64)

  const float inv_temper = 0.08838834764831845f;  // 1/sqrt(128)
  const int* seq_c = seq + (size_t)c * N_;

  // ---- H slab into registers once: A-frag layout [m=mrow][k contiguous]
  bf16x8 Ha[8];
  {
    const float* hrow = hidden + (size_t)(l0 + lsl * 32 + mrow) * D_ + hi * 8;
    #pragma unroll
    for (int ks = 0; ks < 8; ++ks) {
      f32x4 h0 = *(const f32x4*)(hrow + ks * 16);
      f32x4 h1 = *(const f32x4*)(hrow + ks * 16 + 4);
      Ha[ks] = (bf16x8){ (bf16_t)h0[0], (bf16_t)h0[1], (bf16_t)h0[2], (bf16_t)h0[3],
                         (bf16_t)h1[0], (bf16_t)h1[1], (bf16_t)h1[2], (bf16_t)h1[3] };
    }
  }

  // lane-constant pieces of per-iter addressing
  const int lrow_base = lsl * 32 + 4 * hi;          // + (r&3) + 8*(r>>2)
  const int ncol      = nh * 64 + mrow;             // + cb*32
  const float* mrow_base = mask + ((size_t)c * L_ + l0 + lrow_base) * N_ + ncol;

  int   sidxB[4];     // seq indices for the NEXT tile's gather
  f32x4 ereg[8];      // prefetched Wemb rows (fp32) for the CURRENT tile
  float mreg[32];     // prefetched mask values for the CURRENT tile

  // ---- preloop pipeline fill
  {
    int sidxA[4];
    #pragma unroll
    for (int rep = 0; rep < 2; ++rep) {
      int u = tid + rep * 512, np = u & 63;
      sidxA[2 * rep + 0] = seq_c[2 * np];
      sidxA[2 * rep + 1] = seq_c[2 * np + 1];
    }
    #pragma unroll
    for (int rep = 0; rep < 2; ++rep) {
      int u = tid + rep * 512, g = u >> 6;
      const f32x4* r1 = (const f32x4*)(Wemb + (size_t)sidxA[2 * rep + 0] * D_ + g * 8);
      const f32x4* r2 = (const f32x4*)(Wemb + (size_t)sidxA[2 * rep + 1] * D_ + g * 8);
      ereg[4 * rep + 0] = r1[0]; ereg[4 * rep + 1] = r1[1];
      ereg[4 * rep + 2] = r2[0]; ereg[4 * rep + 3] = r2[1];
    }
    #pragma unroll
    for (int rep = 0; rep < 2; ++rep) {            // seq for tile 1
      int u = tid + rep * 512, np = u & 63;
      sidxB[2 * rep + 0] = seq_c[128 + 2 * np];
      sidxB[2 * rep + 1] = seq_c[128 + 2 * np + 1];
    }
    #pragma unroll
    for (int r = 0; r < 16; ++r) {                 // mask tile 0 (nontemporal stream)
      const float* mp = mrow_base + (size_t)((r & 3) + 8 * (r >> 2)) * N_;
      mreg[2 * r + 0] = __builtin_nontemporal_load(mp);
      mreg[2 * r + 1] = __builtin_nontemporal_load(mp + 32);
    }
  }

  f32x16 Oacc0, Oacc1;
  float dacc[16];
  #pragma unroll
  for (int i = 0; i < 16; ++i) { Oacc0[i] = 0.f; Oacc1[i] = 0.f; dacc[i] = 0.f; }

  #pragma unroll 1
  for (int nt = 0; nt < 32; ++nt) {
    __syncthreads();   // prev GEMM2 done reading End/Et/Ps

    // ---- stage E tile from prefetched regs (dual layout)
    #pragma unroll
    for (int rep = 0; rep < 2; ++rep) {
      int u = tid + rep * 512;
      int np = u & 63, g = u >> 6;
      int n1 = 2 * np, n2 = n1 + 1;
      f32x4 a0 = ereg[4 * rep + 0], a1 = ereg[4 * rep + 1];
      f32x4 b0 = ereg[4 * rep + 2], b1 = ereg[4 * rep + 3];
      bf16x8 e1 = { (bf16_t)a0[0], (bf16_t)a0[1], (bf16_t)a0[2], (bf16_t)a0[3],
                    (bf16_t)a1[0], (bf16_t)a1[1], (bf16_t)a1[2], (bf16_t)a1[3] };
      bf16x8 e2 = { (bf16_t)b0[0], (bf16_t)b0[1], (bf16_t)b0[2], (bf16_t)b0[3],
                    (bf16_t)b1[0], (bf16_t)b1[1], (bf16_t)b1[2], (bf16_t)b1[3] };
      *(bf16x8*)&End[n1][g * 8] = e1;
      *(bf16x8*)&End[n2][g * 8] = e2;
      #pragma unroll
      for (int i = 0; i < 8; ++i) {
        bf16x2 t = { e1[i], e2[i] };
        *(bf16x2*)&Et[g * 8 + i][n1] = t;
      }
    }
    __syncthreads();

    // ---- GEMM1: S[l][n] = H . E^T   (C cols = n -> mask is lane-coalesced)
    f32x16 S0, S1;
    #pragma unroll
    for (int i = 0; i < 16; ++i) { S0[i] = 0.f; S1[i] = 0.f; }
    #pragma unroll
    for (int ks = 0; ks < 8; ++ks) {
      bf16x8 b0 = *(const bf16x8*)&End[nh * 64 + 0  + mrow][ks * 16 + hi * 8];
      bf16x8 b1 = *(const bf16x8*)&End[nh * 64 + 32 + mrow][ks * 16 + hi * 8];
      S0 = __builtin_amdgcn_mfma_f32_32x32x16_bf16(Ha[ks], b0, S0, 0, 0, 0);
      S1 = __builtin_amdgcn_mfma_f32_32x32x16_bf16(Ha[ks], b1, S1, 0, 0, 0);
    }

    // ---- issue next tile's gather (seq arrived >=1 iter ago; regs free after stage)
    {
      int ntp = (nt < 31) ? nt + 1 : 31;
      #pragma unroll
      for (int rep = 0; rep < 2; ++rep) {
        int u = tid + rep * 512, g = u >> 6;
        const f32x4* r1 = (const f32x4*)(Wemb + (size_t)sidxB[2 * rep + 0] * D_ + g * 8);
        const f32x4* r2 = (const f32x4*)(Wemb + (size_t)sidxB[2 * rep + 1] * D_ + g * 8);
        ereg[4 * rep + 0] = r1[0]; ereg[4 * rep + 1] = r1[1];
        ereg[4 * rep + 2] = r2[0]; ereg[4 * rep + 3] = r2[1];
      }
      int nts = (nt < 30) ? nt + 2 : 31;           // seq two tiles ahead
      const int* sp = seq_c + nts * 128;
      #pragma unroll
      for (int rep = 0; rep < 2; ++rep) {
        int u = tid + rep * 512, np = u & 63;
        sidxB[2 * rep + 0] = sp[2 * np];
        sidxB[2 * rep + 1] = sp[2 * np + 1];
      }
      (void)ntp;
    }

    // ---- exp * mask -> P (LDS) + running denominators
    #pragma unroll
    for (int r = 0; r < 16; ++r) {
      int lr = lsl * 32 + (r & 3) + 8 * (r >> 2) + 4 * hi;
      float m0 = fminf(fmaxf(mreg[2 * r + 0], 0.f), 1.f);
      float m1 = fminf(fmaxf(mreg[2 * r + 1], 0.f), 1.f);
      float w0 = __expf(S0[r] * inv_temper) * m0;
      float w1 = __expf(S1[r] * inv_temper) * m1;
      dacc[r] += w0 + w1;
      Ps[lr][nh * 64 + mrow]      = (bf16_t)w0;
      Ps[lr][nh * 64 + 32 + mrow] = (bf16_t)w1;
    }

    // ---- issue next tile's mask stream (in flight across GEMM2 + stage + GEMM1)
    {
      int ntp = (nt < 31) ? nt + 1 : 31;
      const float* mb = mrow_base + (size_t)ntp * 128;
      #pragma unroll
      for (int r = 0; r < 16; ++r) {
        const float* mp = mb + (size_t)((r & 3) + 8 * (r >> 2)) * N_;
        mreg[2 * r + 0] = __builtin_nontemporal_load(mp);
        mreg[2 * r + 1] = __builtin_nontemporal_load(mp + 32);
      }
    }
    __syncthreads();   // Ps visible

    // ---- GEMM2: O[l][d] += P . E
    #pragma unroll
    for (int ks = 0; ks < 8; ++ks) {
      bf16x8 a  = *(const bf16x8*)&Ps[lsl * 32 + mrow][ks * 16 + hi * 8];
      bf16x8 b0 = *(const bf16x8*)&Et[nh * 64 + 0  + mrow][ks * 16 + hi * 8];
      bf16x8 b1 = *(const bf16x8*)&Et[nh * 64 + 32 + mrow][ks * 16 + hi * 8];
      Oacc0 = __builtin_amdgcn_mfma_f32_32x32x16_bf16(a, b0, Oacc0, 0, 0, 0);
      Oacc1 = __builtin_amdgcn_mfma_f32_32x32x16_bf16(a, b1, Oacc1, 0, 0, 0);
    }
  }

  // ---- finalize denominators: reduce dacc over the 32 n-lanes per half, then 2 halves
  #pragma unroll
  for (int r = 0; r < 16; ++r) {
    float v = dacc[r];
    v += __shfl_xor(v, 1, 64);
    v += __shfl_xor(v, 2, 64);
    v += __shfl_xor(v, 4, 64);
    v += __shfl_xor(v, 8, 64);
    v += __shfl_xor(v, 16, 64);
    if (mrow == 0)
      dpart[nh][lsl * 32 + (r & 3) + 8 * (r >> 2) + 4 * hi] = v;
  }
  __syncthreads();
  if (tid < 128)
    dinv[tid] = 1.0f / (dpart[0][tid] + dpart[1][tid] + 1e-10f);
  __syncthreads();

  // ---- epilogue: normalize + nontemporal store
  #pragma unroll
  for (int r = 0; r < 16; ++r) {
    int lr = lsl * 32 + (r & 3) + 8 * (r >> 2) + 4 * hi;
    float inv = dinv[lr];
    size_t base = (size_t)(l0 + lr) * (C_ * D_) + c * D_ + nh * 64 + mrow;
    __builtin_nontemporal_store(Oacc0[r] * inv, out + base);
    __builtin_nontemporal_store(Oacc1[r] * inv, out + base + 32);
  }
}

extern "C" void kernel_launch(void* const* d_in, const int* in_sizes, int n_in,
                              void* d_out, int out_size, void* d_ws, size_t ws_size,
                              hipStream_t stream) {
  (void)in_sizes; (void)n_in; (void)out_size; (void)d_ws; (void)ws_size;
  const int*   seq    = (const int*)d_in[0];
  const float* hidden = (const float*)d_in[1];
  const float* mask   = (const float*)d_in[2];
  // d_in[3] = channel_ids (unused), d_in[5] = W_channel (softmax over size-1 dim == 1)
  const float* Wemb   = (const float*)d_in[4];
  float* out = (float*)d_out;
  ngram_attn_kernel<<<dim3(256), dim3(512), 0, stream>>>(seq, hidden, mask, Wemb, out);
}